// Round 2
// baseline (994.917 us; speedup 1.0000x reference)
//
#include <hip/hip_runtime.h>
#include <hip/hip_bf16.h>

using bf16_t = __bf16;
typedef __bf16 bf16x8 __attribute__((ext_vector_type(8)));
typedef __bf16 bf16x4 __attribute__((ext_vector_type(4)));
typedef float  f32x4  __attribute__((ext_vector_type(4)));

#define MFMA16(a,b,c) __builtin_amdgcn_mfma_f32_16x16x32_bf16((a),(b),(c),0,0,0)

// ---------------------------------------------------------------------------
// fp32 -> bf16 elementwise convert (x). 4 elems/thread.
// ---------------------------------------------------------------------------
__global__ __launch_bounds__(256) void cvt_f2b(const float* __restrict__ in,
                                               bf16_t* __restrict__ out)
{
  const size_t i = ((size_t)blockIdx.x * 256 + threadIdx.x) * 4;
  f32x4 d = *(const f32x4*)(in + i);
  bf16x4 o;
#pragma unroll
  for (int j = 0; j < 4; ++j) o[j] = (bf16_t)d[j];
  *(bf16x4*)(out + i) = o;
}

// ---------------------------------------------------------------------------
// fp32 [R][C] -> bf16 [C][R] transposed convert (weights). 64x64 LDS tile.
// ---------------------------------------------------------------------------
__global__ __launch_bounds__(256) void cvt_transpose(const float* __restrict__ in,
                                                     bf16_t* __restrict__ out,
                                                     int R, int C)
{
  __shared__ __align__(16) bf16_t t[64 * 80];
  const int r0 = blockIdx.y * 64, c0 = blockIdx.x * 64;
  const int rr = threadIdx.x >> 4;          // 0..15
  const int c4 = (threadIdx.x & 15) * 4;    // 0..60
#pragma unroll
  for (int i = 0; i < 4; ++i) {
    const int r = rr + i * 16;
    f32x4 d = *(const f32x4*)(in + (size_t)(r0 + r) * C + c0 + c4);
#pragma unroll
    for (int j = 0; j < 4; ++j) t[(c4 + j) * 80 + r] = (bf16_t)d[j];
  }
  __syncthreads();
  const int a  = threadIdx.x >> 3;          // 0..31
  const int bc = (threadIdx.x & 7) * 8;
#pragma unroll
  for (int half = 0; half < 2; ++half) {
    const int cc = a + half * 32;
    bf16x8 d = *(const bf16x8*)&t[cc * 80 + bc];
    *(bf16x8*)(out + (size_t)(c0 + cc) * R + r0 + bc) = d;
  }
}

// ---------------------------------------------------------------------------
// GEMM: C[M,N] = A[M,K] @ B[K,N], B given transposed as BT[N,K]. bf16 in,
// fp32 accum, OutT out. 64x64 tile, 4 waves of 32x32 (2x2 MFMA 16x16x32).
// LDS stride 40 bf16 (80B): max 2-way bank aliasing (free on CDNA4).
// ---------------------------------------------------------------------------
template <typename OutT>
__global__ __launch_bounds__(256) void gemm_bt(const bf16_t* __restrict__ A,
                                               const bf16_t* __restrict__ BT,
                                               OutT* __restrict__ C,
                                               int M, int N, int K)
{
  __shared__ __align__(16) bf16_t As[64 * 40];
  __shared__ __align__(16) bf16_t Bs[64 * 40];
  const int tid  = threadIdx.x;
  const int m0   = blockIdx.y * 64, n0 = blockIdx.x * 64;
  const int lane = tid & 63, w = tid >> 6;
  const int quad = lane >> 4, l15 = lane & 15;
  const int wm = (w >> 1) * 32, wn = (w & 1) * 32;
  const int srow = tid >> 2, scg = (tid & 3) * 8;

  f32x4 acc[2][2] = {};

  for (int k0 = 0; k0 < K; k0 += 32) {
    bf16x8 av = *(const bf16x8*)(A  + (size_t)(m0 + srow) * K + k0 + scg);
    bf16x8 bv = *(const bf16x8*)(BT + (size_t)(n0 + srow) * K + k0 + scg);
    __syncthreads();                       // prior iter's fragment reads done
    *(bf16x8*)&As[srow * 40 + scg] = av;
    *(bf16x8*)&Bs[srow * 40 + scg] = bv;
    __syncthreads();                       // tiles visible
    bf16x8 a0 = *(const bf16x8*)&As[(wm      + l15) * 40 + quad * 8];
    bf16x8 a1 = *(const bf16x8*)&As[(wm + 16 + l15) * 40 + quad * 8];
    bf16x8 b0 = *(const bf16x8*)&Bs[(wn      + l15) * 40 + quad * 8];
    bf16x8 b1 = *(const bf16x8*)&Bs[(wn + 16 + l15) * 40 + quad * 8];
    acc[0][0] = MFMA16(a0, b0, acc[0][0]);
    acc[0][1] = MFMA16(a0, b1, acc[0][1]);
    acc[1][0] = MFMA16(a1, b0, acc[1][0]);
    acc[1][1] = MFMA16(a1, b1, acc[1][1]);
  }

#pragma unroll
  for (int i = 0; i < 2; ++i)
#pragma unroll
    for (int j = 0; j < 2; ++j)
#pragma unroll
      for (int r = 0; r < 4; ++r) {
        const int row = m0 + wm + i * 16 + quad * 4 + r;   // C/D: row = quad*4+reg
        const int col = n0 + wn + j * 16 + l15;            //      col = lane&15
        C[(size_t)row * N + col] = (OutT)acc[i][j][r];
      }
}

// ---------------------------------------------------------------------------
// bf16 64x64 tiled transpose with (b,h) z-split — used for V -> vT.
// ---------------------------------------------------------------------------
__global__ __launch_bounds__(256) void transpose_bf16(const bf16_t* __restrict__ in,
                                                      bf16_t* __restrict__ out,
                                                      long long in_rs, long long out_rs,
                                                      long long in_zs1, long long in_zs2,
                                                      long long out_zs)
{
  __shared__ __align__(16) bf16_t t[64 * 80];
  const int z = blockIdx.z;
  in  += (size_t)(z >> 4) * in_zs1 + (size_t)(z & 15) * in_zs2;
  out += (size_t)z * out_zs;
  const int r0 = blockIdx.y * 64, c0 = blockIdx.x * 64;
  const int a  = threadIdx.x >> 3;
  const int bc = (threadIdx.x & 7) * 8;
#pragma unroll
  for (int half = 0; half < 2; ++half) {
    const int rr = a + half * 32;
    bf16x8 d = *(const bf16x8*)(in + (size_t)(r0 + rr) * in_rs + c0 + bc);
#pragma unroll
    for (int j = 0; j < 8; ++j) t[(bc + j) * 80 + rr] = d[j];
  }
  __syncthreads();
#pragma unroll
  for (int half = 0; half < 2; ++half) {
    const int cc = a + half * 32;
    bf16x8 d = *(const bf16x8*)&t[cc * 80 + bc];
    *(bf16x8*)(out + (size_t)(c0 + cc) * out_rs + r0 + bc) = d;
  }
}

// ---------------------------------------------------------------------------
// latent_prev fp32 (2,2048,512) -> bf16 latent rows [0,2048) of (2,4096,512)
// ---------------------------------------------------------------------------
__global__ __launch_bounds__(256) void copy_prev_f(const float* __restrict__ prev,
                                                   bf16_t* __restrict__ latent)
{
  const size_t v    = (size_t)blockIdx.x * 256 + threadIdx.x;   // 0..524287
  const size_t flat = v * 4;
  const size_t per  = (size_t)2048 * 512;
  const size_t b    = flat / per, rem = flat % per;
  f32x4 d = *(const f32x4*)(prev + flat);
  bf16x4 o;
#pragma unroll
  for (int j = 0; j < 4; ++j) o[j] = (bf16_t)d[j];
  *(bf16x4*)(latent + b * ((size_t)4096 * 512) + rem) = o;
}

// ---------------------------------------------------------------------------
// LayerNorm over 512 (fp32 stats), bf16 in, fp32 g/b, bf16 out into latent
// rows [2048,4096).
// ---------------------------------------------------------------------------
__global__ __launch_bounds__(256) void ln_kernel(const bf16_t* __restrict__ in,
                                                 const float* __restrict__ g_,
                                                 const float* __restrict__ b_,
                                                 bf16_t* __restrict__ latent)
{
  const int row = blockIdx.x;             // 0..4095 (= b*2048 + t)
  const int tid = threadIdx.x;
  const float x0 = (float)in[(size_t)row * 512 + tid];
  const float x1 = (float)in[(size_t)row * 512 + 256 + tid];
  float s  = x0 + x1;
  float sq = x0 * x0 + x1 * x1;
#pragma unroll
  for (int off = 1; off < 64; off <<= 1) {
    s  += __shfl_xor(s, off);
    sq += __shfl_xor(sq, off);
  }
  __shared__ float red[8];
  const int w = tid >> 6;
  if ((tid & 63) == 0) { red[w] = s; red[4 + w] = sq; }
  __syncthreads();
  s  = red[0] + red[1] + red[2] + red[3];
  sq = red[4] + red[5] + red[6] + red[7];
  const float mu   = s * (1.0f / 512.0f);
  const float var  = sq * (1.0f / 512.0f) - mu * mu;
  const float rstd = rsqrtf(var + 1e-5f);
  const int b = row >> 11, tt = row & 2047;
  bf16_t* outp = latent + ((size_t)b * 4096 + 2048 + tt) * 512;
  outp[tid]       = (bf16_t)((x0 - mu) * rstd * g_[tid]       + b_[tid]);
  outp[tid + 256] = (bf16_t)((x1 - mu) * rstd * g_[tid + 256] + b_[tid + 256]);
}

// ---------------------------------------------------------------------------
// Flash attention. grid = b*H*32; block = 4 waves; q-tile 64 rows (16/wave).
// K frags direct from global; V from vT (b,H,hd,S) staged to LDS.
// Online softmax; P LDS round-trip C->A layout. past_len = 2048.
// ---------------------------------------------------------------------------
__global__ __launch_bounds__(256) void attn_kernel(const bf16_t* __restrict__ q,
                                                   const bf16_t* __restrict__ k,
                                                   const bf16_t* __restrict__ vT,
                                                   bf16_t* __restrict__ out)
{
  __shared__ __align__(16) bf16_t Vt[128 * 40];   // [hd][key] stride 40
  __shared__ __align__(16) bf16_t P[4][16 * 40];  // per-wave [qrow][key]
  const int tid  = threadIdx.x;
  const int w    = tid >> 6, lane = tid & 63;
  const int quad = lane >> 4, l15 = lane & 15;
  const int qt   = blockIdx.x & 31;
  const int h    = (blockIdx.x >> 5) & 15;
  const int b    = blockIdx.x >> 9;
  const int q0   = qt * 64;

  const bf16_t* qbase = q + ((size_t)(b * 2048 + q0 + w * 16 + l15)) * 2048 + h * 128 + quad * 8;
  bf16x8 qf[4];
#pragma unroll
  for (int c = 0; c < 4; ++c) qf[c] = *(const bf16x8*)(qbase + c * 32);

  f32x4 o[8] = {};
  float m_r[4] = {-1e30f, -1e30f, -1e30f, -1e30f};
  float l_r[4] = {0.f, 0.f, 0.f, 0.f};

  const int send = 2048 + q0 + 64;                 // exclusive key bound
  const int vhd  = tid >> 1;                       // 0..127
  const int vkc  = (tid & 1) * 16;
  const bf16_t* vrow = vT + ((size_t)(b * 16 + h) * 128 + vhd) * 4096;

  for (int s0 = 0; s0 < send; s0 += 32) {
    __syncthreads();                               // prior PV reads of Vt done
    {
      bf16x8 v0 = *(const bf16x8*)(vrow + s0 + vkc);
      bf16x8 v1 = *(const bf16x8*)(vrow + s0 + vkc + 8);
      *(bf16x8*)&Vt[vhd * 40 + vkc]     = v0;
      *(bf16x8*)&Vt[vhd * 40 + vkc + 8] = v1;
    }
    f32x4 sc[2] = {};
#pragma unroll
    for (int g = 0; g < 2; ++g) {
      const bf16_t* kbase = k + ((size_t)(b * 4096 + s0 + g * 16 + l15)) * 2048 + h * 128 + quad * 8;
#pragma unroll
      for (int c = 0; c < 4; ++c) {
        bf16x8 kf = *(const bf16x8*)(kbase + c * 32);
        sc[g] = MFMA16(qf[c], kf, sc[g]);
      }
    }
    const float scale = 0.08838834764831845f;      // 1/sqrt(128)
#pragma unroll
    for (int r = 0; r < 4; ++r) {
      const int qi = q0 + w * 16 + quad * 4 + r;
      float s0v = sc[0][r] * scale;
      float s1v = sc[1][r] * scale;
      if (s0 + l15 > 2048 + qi)      s0v = -1e30f;
      if (s0 + 16 + l15 > 2048 + qi) s1v = -1e30f;
      float mx = fmaxf(s0v, s1v);
#pragma unroll
      for (int off = 1; off < 16; off <<= 1) mx = fmaxf(mx, __shfl_xor(mx, off));
      const float mnew = fmaxf(m_r[r], mx);
      const float p0 = __expf(s0v - mnew);
      const float p1 = __expf(s1v - mnew);
      float rs = p0 + p1;
#pragma unroll
      for (int off = 1; off < 16; off <<= 1) rs += __shfl_xor(rs, off);
      const float alpha = __expf(m_r[r] - mnew);
      l_r[r] = l_r[r] * alpha + rs;
      m_r[r] = mnew;
#pragma unroll
      for (int c = 0; c < 8; ++c) o[c][r] *= alpha;
      P[w][(quad * 4 + r) * 40 + l15]      = (bf16_t)p0;
      P[w][(quad * 4 + r) * 40 + 16 + l15] = (bf16_t)p1;
    }
    bf16x8 pf = *(const bf16x8*)&P[w][l15 * 40 + quad * 8];
    __syncthreads();                               // Vt staged
#pragma unroll
    for (int c = 0; c < 8; ++c) {
      bf16x8 vf = *(const bf16x8*)&Vt[(c * 16 + l15) * 40 + quad * 8];
      o[c] = MFMA16(pf, vf, o[c]);
    }
  }

#pragma unroll
  for (int c = 0; c < 8; ++c)
#pragma unroll
    for (int r = 0; r < 4; ++r) {
      const int row = b * 2048 + q0 + w * 16 + quad * 4 + r;
      out[(size_t)row * 2048 + h * 128 + c * 16 + l15] = (bf16_t)(o[c][r] / l_r[r]);
    }
}

// ---------------------------------------------------------------------------
extern "C" void kernel_launch(void* const* d_in, const int* in_sizes, int n_in,
                              void* d_out, int out_size, void* d_ws, size_t ws_size,
                              hipStream_t stream)
{
  (void)in_sizes; (void)n_in; (void)out_size; (void)ws_size;
  const float* x        = (const float*)d_in[0];
  const float* lat_prev = (const float*)d_in[1];
  const float* Wq       = (const float*)d_in[2];
  const float* Wdown    = (const float*)d_in[3];
  const float* Wk_up    = (const float*)d_in[4];
  const float* Wv_up    = (const float*)d_in[5];
  const float* ln_g     = (const float*)d_in[6];
  const float* ln_b     = (const float*)d_in[7];
  const float* Wo       = (const float*)d_in[8];
  float* out = (float*)d_out;

  char* p = (char*)d_ws;
  auto alloc = [&](size_t elems) { bf16_t* r = (bf16_t*)p; p += elems * 2; return r; };
  bf16_t* xb     = alloc((size_t)4096 * 2048);   // also hosts WoT after x dead
  bf16_t* WqT    = alloc((size_t)2048 * 2048);
  bf16_t* WdT    = alloc((size_t)512 * 2048);
  bf16_t* qbuf   = alloc((size_t)4096 * 2048);
  bf16_t* latpre = alloc((size_t)4096 * 512);    // also hosts WkT+WvT after LN
  bf16_t* latent = alloc((size_t)2 * 4096 * 512);
  bf16_t* kbuf   = alloc((size_t)8192 * 2048);
  bf16_t* vbuf   = alloc((size_t)8192 * 2048);   // also hosts aout after vT
  bf16_t* vTb    = alloc((size_t)8192 * 2048);
  bf16_t* WoT  = xb;                              // alias (after latpre gemm)
  bf16_t* WkT  = latpre;                          // alias (after ln_kernel)
  bf16_t* WvT  = latpre + (size_t)2048 * 512;     // alias
  bf16_t* aout = vbuf;                            // alias (after vT transpose)

  const dim3 B(256);
  // ingest: convert x, transpose+convert Wq/Wdown
  cvt_f2b<<<dim3(8192), B, 0, stream>>>(x, xb);
  cvt_transpose<<<dim3(32, 32), B, 0, stream>>>(Wq,    WqT, 2048, 2048);
  cvt_transpose<<<dim3(8,  32), B, 0, stream>>>(Wdown, WdT, 2048, 512);
  // projections from x
  gemm_bt<<<dim3(32, 64), B, 0, stream>>>(xb, WqT, qbuf,   4096, 2048, 2048);
  gemm_bt<<<dim3(8,  64), B, 0, stream>>>(xb, WdT, latpre, 4096,  512, 2048);
  // latent cache
  copy_prev_f<<<dim3(2048), B, 0, stream>>>(lat_prev, latent);
  ln_kernel<<<dim3(4096), B, 0, stream>>>(latpre, ln_g, ln_b, latent);
  // weight transposes into dead regions (ordering on stream enforces lifetime)
  cvt_transpose<<<dim3(32, 32), B, 0, stream>>>(Wo,    WoT, 2048, 2048);
  cvt_transpose<<<dim3(32, 8),  B, 0, stream>>>(Wk_up, WkT, 512, 2048);
  cvt_transpose<<<dim3(32, 8),  B, 0, stream>>>(Wv_up, WvT, 512, 2048);
  // k, v up-projections
  gemm_bt<<<dim3(32, 128), B, 0, stream>>>(latent, WkT, kbuf, 8192, 2048, 512);
  gemm_bt<<<dim3(32, 128), B, 0, stream>>>(latent, WvT, vbuf, 8192, 2048, 512);
  // v -> vT (b,H,hd,S)
  transpose_bf16<<<dim3(2, 64, 32), B, 0, stream>>>(vbuf, vTb, 2048, 4096,
                                                    (long long)4096 * 2048, 128,
                                                    (long long)128 * 4096);
  // attention
  attn_kernel<<<dim3(1024), B, 0, stream>>>(qbuf, kbuf, vTb, aout);
  // output projection (fp32 out)
  gemm_bt<<<dim3(32, 64), B, 0, stream>>>(aout, WoT, out, 4096, 2048, 2048);
}

// Round 3
// 637.798 us; speedup vs baseline: 1.5599x; 1.5599x over previous
//
#include <hip/hip_runtime.h>
#include <hip/hip_bf16.h>

using bf16_t = __bf16;
typedef __bf16 bf16x8 __attribute__((ext_vector_type(8)));
typedef __bf16 bf16x4 __attribute__((ext_vector_type(4)));
typedef float  f32x4  __attribute__((ext_vector_type(4)));
typedef float  f32x16 __attribute__((ext_vector_type(16)));

#define MFMA16(a,b,c) __builtin_amdgcn_mfma_f32_16x16x32_bf16((a),(b),(c),0,0,0)
#define MFMA32(a,b,c) __builtin_amdgcn_mfma_f32_32x32x16_bf16((a),(b),(c),0,0,0)

__device__ __forceinline__ void load_lds16(const void* g, void* l) {
  __builtin_amdgcn_global_load_lds(
      (const __attribute__((address_space(1))) unsigned int*)g,
      (__attribute__((address_space(3))) unsigned int*)l, 16, 0, 0);
}

// ---------------------------------------------------------------------------
// fp32 -> bf16 elementwise convert (x). 4 elems/thread.
// ---------------------------------------------------------------------------
__global__ __launch_bounds__(256) void cvt_f2b(const float* __restrict__ in,
                                               bf16_t* __restrict__ out)
{
  const size_t i = ((size_t)blockIdx.x * 256 + threadIdx.x) * 4;
  f32x4 d = *(const f32x4*)(in + i);
  bf16x4 o;
#pragma unroll
  for (int j = 0; j < 4; ++j) o[j] = (bf16_t)d[j];
  *(bf16x4*)(out + i) = o;
}

// ---------------------------------------------------------------------------
// fp32 [R][C] -> bf16 [C][R] transposed convert (weights). 64x64 LDS tile.
// ---------------------------------------------------------------------------
__global__ __launch_bounds__(256) void cvt_transpose(const float* __restrict__ in,
                                                     bf16_t* __restrict__ out,
                                                     int R, int C)
{
  __shared__ __align__(16) bf16_t t[64 * 80];
  const int r0 = blockIdx.y * 64, c0 = blockIdx.x * 64;
  const int rr = threadIdx.x >> 4;          // 0..15
  const int c4 = (threadIdx.x & 15) * 4;    // 0..60
#pragma unroll
  for (int i = 0; i < 4; ++i) {
    const int r = rr + i * 16;
    f32x4 d = *(const f32x4*)(in + (size_t)(r0 + r) * C + c0 + c4);
#pragma unroll
    for (int j = 0; j < 4; ++j) t[(c4 + j) * 80 + r] = (bf16_t)d[j];
  }
  __syncthreads();
  const int a  = threadIdx.x >> 3;          // 0..31
  const int bc = (threadIdx.x & 7) * 8;
#pragma unroll
  for (int half = 0; half < 2; ++half) {
    const int cc = a + half * 32;
    bf16x8 d = *(const bf16x8*)&t[cc * 80 + bc];
    *(bf16x8*)(out + (size_t)(c0 + cc) * R + r0 + bc) = d;
  }
}

// ---------------------------------------------------------------------------
// m97-class GEMM: C[M,N] = A[M,K] @ B[K,N] (+scale), B given as BT[N,K].
// 128x128 tile, BK=32, 4 waves each 64x64 (4x4 of 16x16x32 MFMA).
// Staging via global_load_lds dwordx4; XOR chunk swizzle kills the
// no-padding 4-way read conflicts (phys_chunk = chunk ^ (row&3)).
// ---------------------------------------------------------------------------
template <typename OutT>
__global__ __launch_bounds__(256) void gemm128(const bf16_t* __restrict__ A,
                                               const bf16_t* __restrict__ BT,
                                               OutT* __restrict__ C,
                                               int M, int N, int K, float scale,
                                               long long zB, long long zC)
{
  __shared__ __align__(16) bf16_t As[128 * 32];
  __shared__ __align__(16) bf16_t Bs[128 * 32];
  const int tid = threadIdx.x;
  BT += (size_t)blockIdx.z * zB;
  C  += (size_t)blockIdx.z * zC;
  const int m0 = blockIdx.y * 128, n0 = blockIdx.x * 128;
  const int lane = tid & 63, w = tid >> 6;
  const int quad = lane >> 4, l15 = lane & 15;
  const int wm = (w >> 1) * 64, wn = (w & 1) * 64;
  // staging: slot = tid + 256p: row = slot>>2 (p0:0..63, p1:64..127), phys=tid&3
  const int s_row = tid >> 2;
  const int g_off = ((tid & 3) ^ (s_row & 3)) * 8;   // swizzled global chunk
  const int quadp = (quad ^ (l15 & 3)) * 8;          // swizzled frag offset
  const bf16_t* Ap0 = A  + (size_t)(m0 + s_row) * K + g_off;
  const bf16_t* Ap1 = A  + (size_t)(m0 + 64 + s_row) * K + g_off;
  const bf16_t* Bp0 = BT + (size_t)(n0 + s_row) * K + g_off;
  const bf16_t* Bp1 = BT + (size_t)(n0 + 64 + s_row) * K + g_off;

  f32x4 acc[4][4] = {};

  for (int k0 = 0; k0 < K; k0 += 32) {
    __syncthreads();                        // prior iter's frag reads done
    load_lds16(Ap0 + k0, As + tid * 8);
    load_lds16(Ap1 + k0, As + tid * 8 + 2048);
    load_lds16(Bp0 + k0, Bs + tid * 8);
    load_lds16(Bp1 + k0, Bs + tid * 8 + 2048);
    __syncthreads();                        // tiles resident
    bf16x8 af[4], bfr[4];
#pragma unroll
    for (int fi = 0; fi < 4; ++fi)
      af[fi] = *(const bf16x8*)&As[(wm + fi * 16 + l15) * 32 + quadp];
#pragma unroll
    for (int fj = 0; fj < 4; ++fj)
      bfr[fj] = *(const bf16x8*)&Bs[(wn + fj * 16 + l15) * 32 + quadp];
#pragma unroll
    for (int fi = 0; fi < 4; ++fi)
#pragma unroll
      for (int fj = 0; fj < 4; ++fj)
        acc[fi][fj] = MFMA16(af[fi], bfr[fj], acc[fi][fj]);
  }

#pragma unroll
  for (int fi = 0; fi < 4; ++fi)
#pragma unroll
    for (int fj = 0; fj < 4; ++fj)
#pragma unroll
      for (int r = 0; r < 4; ++r) {
        const int row = m0 + wm + fi * 16 + quad * 4 + r;
        const int col = n0 + wn + fj * 16 + l15;
        C[(size_t)row * N + col] = (OutT)(acc[fi][fj][r] * scale);
      }
}

// ---------------------------------------------------------------------------
// latent_prev fp32 (2,2048,512) -> bf16 latent rows [0,2048) of (2,4096,512)
// ---------------------------------------------------------------------------
__global__ __launch_bounds__(256) void copy_prev_f(const float* __restrict__ prev,
                                                   bf16_t* __restrict__ latent)
{
  const size_t v    = (size_t)blockIdx.x * 256 + threadIdx.x;
  const size_t flat = v * 4;
  const size_t per  = (size_t)2048 * 512;
  const size_t b    = flat / per, rem = flat % per;
  f32x4 d = *(const f32x4*)(prev + flat);
  bf16x4 o;
#pragma unroll
  for (int j = 0; j < 4; ++j) o[j] = (bf16_t)d[j];
  *(bf16x4*)(latent + b * ((size_t)4096 * 512) + rem) = o;
}

// ---------------------------------------------------------------------------
// LayerNorm over 512 (fp32 stats), bf16 in, fp32 g/b, bf16 out into latent
// rows [2048,4096).
// ---------------------------------------------------------------------------
__global__ __launch_bounds__(256) void ln_kernel(const bf16_t* __restrict__ in,
                                                 const float* __restrict__ g_,
                                                 const float* __restrict__ b_,
                                                 bf16_t* __restrict__ latent)
{
  const int row = blockIdx.x;             // 0..4095 (= b*2048 + t)
  const int tid = threadIdx.x;
  const float x0 = (float)in[(size_t)row * 512 + tid];
  const float x1 = (float)in[(size_t)row * 512 + 256 + tid];
  float s  = x0 + x1;
  float sq = x0 * x0 + x1 * x1;
#pragma unroll
  for (int off = 1; off < 64; off <<= 1) {
    s  += __shfl_xor(s, off);
    sq += __shfl_xor(sq, off);
  }
  __shared__ float red[8];
  const int w = tid >> 6;
  if ((tid & 63) == 0) { red[w] = s; red[4 + w] = sq; }
  __syncthreads();
  s  = red[0] + red[1] + red[2] + red[3];
  sq = red[4] + red[5] + red[6] + red[7];
  const float mu   = s * (1.0f / 512.0f);
  const float var  = sq * (1.0f / 512.0f) - mu * mu;
  const float rstd = rsqrtf(var + 1e-5f);
  const int b = row >> 11, tt = row & 2047;
  bf16_t* outp = latent + ((size_t)b * 4096 + 2048 + tt) * 512;
  outp[tid]       = (bf16_t)((x0 - mu) * rstd * g_[tid]       + b_[tid]);
  outp[tid + 256] = (bf16_t)((x1 - mu) * rstd * g_[tid + 256] + b_[tid + 256]);
}

// ---------------------------------------------------------------------------
// Flash attention v2. grid (t/128, H, b); 4 waves; per-lane query column.
// S^T = K·Q^T via 32x32x16 MFMA -> in-register softmax; PV as
// out^T = V^T·P^T (alpha, l lane-uniform). K/V staged via global_load_lds
// with XOR chunk swizzle; P^T via per-wave LDS (b64 writes / b128 reads).
// q input is pre-scaled by 1/sqrt(128) in the q-GEMM epilogue.
// ---------------------------------------------------------------------------
__global__ __launch_bounds__(256) void attn2(const bf16_t* __restrict__ q,
                                             const bf16_t* __restrict__ k,
                                             const bf16_t* __restrict__ vT,
                                             bf16_t* __restrict__ out)
{
  __shared__ __align__(16) char smem[16384 + 16384 + 18432];   // Ks | Vs | Pt
  bf16_t* Ks = (bf16_t*)smem;                 // [64 key][128 feat], swizzled
  bf16_t* Vs = (bf16_t*)(smem + 16384);       // [128 feat][64 key], swizzled
  bf16_t* Pt = (bf16_t*)(smem + 32768);       // 4 x [32 q][72 key]
  bf16_t* Ot = (bf16_t*)smem;                 // epilogue: [128 q'][136 feat]

  const int tid = threadIdx.x;
  const int lane = tid & 63, w = tid >> 6;
  const int l31 = lane & 31, h5 = lane >> 5;
  const int qt = blockIdx.x, h = blockIdx.y, b = blockIdx.z;
  const int q0 = qt * 128;
  const int qg = q0 + l31 * 4 + w;            // this lane's query row

  // Q^T B-frags: B[k=feat fc*16+h5*8+j][n=q l31]
  bf16x8 qf[8];
  const bf16_t* qb = q + ((size_t)(b * 2048 + qg)) * 2048 + h * 128 + h5 * 8;
#pragma unroll
  for (int fc = 0; fc < 8; ++fc) qf[fc] = *(const bf16x8*)(qb + fc * 16);

  const bf16_t* kbase = k + ((size_t)b * 4096) * 2048 + h * 128;
  const bf16_t* vbase = vT + ((size_t)(b * 16 + h)) * 128 * 4096;

  // staging maps (slot = tid + 256p)
  int ks_key[4], ks_go[4], vs_feat[4], vs_go[4];
#pragma unroll
  for (int p = 0; p < 4; ++p) {
    const int slot = tid + 256 * p;
    const int key = slot >> 4, ph = slot & 15;
    ks_key[p] = key;
    ks_go[p]  = (((ph & 8) | ((ph & 7) ^ (key & 7)))) * 8;
    const int ft = slot >> 3, p2 = slot & 7;
    vs_feat[p] = ft;
    vs_go[p]   = (p2 ^ (ft & 7)) * 8;
  }
  // frag read offsets (elems)
  int kfo[8], vfo[4];
#pragma unroll
  for (int fc = 0; fc < 8; ++fc) {
    const int L = fc * 2 + h5;
    kfo[fc] = l31 * 128 + ((L & 8) | ((L & 7) ^ (l31 & 7))) * 8;
  }
#pragma unroll
  for (int kc = 0; kc < 4; ++kc) {
    const int L = kc * 2 + h5;
    vfo[kc] = l31 * 64 + (L ^ (l31 & 7)) * 8;
  }

  f32x16 o[4] = {};
  float m = -1e30f, l = 0.f;
  const int send = 2048 + q0 + 128;

  for (int s0 = 0; s0 < send; s0 += 64) {
    __syncthreads();                          // prior tile reads complete
#pragma unroll
    for (int p = 0; p < 4; ++p) {
      load_lds16(kbase + (size_t)(s0 + ks_key[p]) * 2048 + ks_go[p],
                 Ks + (tid + 256 * p) * 8);
      load_lds16(vbase + (size_t)vs_feat[p] * 4096 + s0 + vs_go[p],
                 Vs + (tid + 256 * p) * 8);
    }
    __syncthreads();                          // tiles resident

    // S^T tiles: rows = keys 32t + (i&3)+8*(i>>2)+4*h5, col = q = l31
    f32x16 st[2] = {};
#pragma unroll
    for (int t = 0; t < 2; ++t)
#pragma unroll
      for (int fc = 0; fc < 8; ++fc) {
        bf16x8 kf = *(const bf16x8*)&Ks[t * 4096 + kfo[fc]];
        st[t] = MFMA32(kf, qf[fc], st[t]);
      }

    if (s0 + 63 > 2048 + q0) {                // causal tail masking
#pragma unroll
      for (int t = 0; t < 2; ++t)
#pragma unroll
        for (int i = 0; i < 16; ++i) {
          const int key = s0 + 32 * t + (i & 3) + 8 * (i >> 2) + 4 * h5;
          if (key > 2048 + qg) st[t][i] = -1e30f;
        }
    }

    // in-register max over this lane's 32 scores + partner half
    float mt = st[0][0];
#pragma unroll
    for (int i = 1; i < 16; ++i) mt = fmaxf(mt, st[0][i]);
#pragma unroll
    for (int i = 0; i < 16; ++i) mt = fmaxf(mt, st[1][i]);
    mt = fmaxf(mt, __shfl_xor(mt, 32));

    if (__any(mt > m)) {                      // rare after warm-up
      const float mnew = fmaxf(m, mt);
      const float alpha = __expf(m - mnew);
#pragma unroll
      for (int ft = 0; ft < 4; ++ft)
#pragma unroll
        for (int i = 0; i < 16; ++i) o[ft][i] *= alpha;
      l *= alpha;
      m = mnew;
    }

    float rs = 0.f;
#pragma unroll
    for (int t = 0; t < 2; ++t)
#pragma unroll
      for (int g = 0; g < 4; ++g) {
        const float p0 = __expf(st[t][4 * g + 0] - m);
        const float p1 = __expf(st[t][4 * g + 1] - m);
        const float p2 = __expf(st[t][4 * g + 2] - m);
        const float p3 = __expf(st[t][4 * g + 3] - m);
        rs += (p0 + p1) + (p2 + p3);
        bf16x4 pk;
        pk[0] = (bf16_t)p0; pk[1] = (bf16_t)p1;
        pk[2] = (bf16_t)p2; pk[3] = (bf16_t)p3;
        // keys 32t + 8g + 4h5 + {0..3} at row q=l31
        *(bf16x4*)&Pt[w * 2304 + l31 * 72 + t * 32 + g * 8 + h5 * 4] = pk;
      }
    rs += __shfl_xor(rs, 32);
    l += rs;

    // out^T += V^T · P^T
#pragma unroll
    for (int kc = 0; kc < 4; ++kc) {
      bf16x8 pf = *(const bf16x8*)&Pt[w * 2304 + l31 * 72 + kc * 16 + h5 * 8];
#pragma unroll
      for (int ft = 0; ft < 4; ++ft) {
        bf16x8 vf = *(const bf16x8*)&Vs[ft * 2048 + vfo[kc]];
        o[ft] = MFMA32(vf, pf, o[ft]);
      }
    }
  }

  // epilogue: normalize, LDS transpose, coalesced store
  __syncthreads();
  const float inv = 1.0f / l;
  const int rowp_w = w * 32 + l31;            // q_local = (rowp&31)*4 + (rowp>>5)
#pragma unroll
  for (int ft = 0; ft < 4; ++ft)
#pragma unroll
    for (int g = 0; g < 4; ++g) {
      bf16x4 pk;
#pragma unroll
      for (int r = 0; r < 4; ++r) pk[r] = (bf16_t)(o[ft][4 * g + r] * inv);
      *(bf16x4*)&Ot[rowp_w * 136 + ft * 32 + g * 8 + h5 * 4] = pk;
    }
  __syncthreads();
#pragma unroll
  for (int p = 0; p < 8; ++p) {
    const int c = tid + 256 * p;
    const int rowp = c >> 4, chk = c & 15;
    const int ql = (rowp & 31) * 4 + (rowp >> 5);
    bf16x8 d = *(const bf16x8*)&Ot[rowp * 136 + chk * 8];
    *(bf16x8*)(out + ((size_t)(b * 2048 + q0 + ql)) * 2048 + h * 128 + chk * 8) = d;
  }
}

// ---------------------------------------------------------------------------
extern "C" void kernel_launch(void* const* d_in, const int* in_sizes, int n_in,
                              void* d_out, int out_size, void* d_ws, size_t ws_size,
                              hipStream_t stream)
{
  (void)in_sizes; (void)n_in; (void)out_size; (void)ws_size;
  const float* x        = (const float*)d_in[0];
  const float* lat_prev = (const float*)d_in[1];
  const float* Wq       = (const float*)d_in[2];
  const float* Wdown    = (const float*)d_in[3];
  const float* Wk_up    = (const float*)d_in[4];
  const float* Wv_up    = (const float*)d_in[5];
  const float* ln_g     = (const float*)d_in[6];
  const float* ln_b     = (const float*)d_in[7];
  const float* Wo       = (const float*)d_in[8];
  float* out = (float*)d_out;

  char* p = (char*)d_ws;
  auto alloc = [&](size_t elems) { bf16_t* r = (bf16_t*)p; p += elems * 2; return r; };
  bf16_t* xb     = alloc((size_t)4096 * 2048);   // hosts WoT after x dead
  bf16_t* WqT    = alloc((size_t)2048 * 2048);
  bf16_t* WdT    = alloc((size_t)512 * 2048);
  bf16_t* qbuf   = alloc((size_t)4096 * 2048);
  bf16_t* latpre = alloc((size_t)4096 * 512);    // hosts WkT+WvT after LN
  bf16_t* latent = alloc((size_t)2 * 4096 * 512);
  bf16_t* kbuf   = alloc((size_t)8192 * 2048);
  bf16_t* vTb    = alloc((size_t)2 * 2048 * 4096);
  bf16_t* aout   = alloc((size_t)4096 * 2048);
  bf16_t* WoT  = xb;
  bf16_t* WkT  = latpre;
  bf16_t* WvT  = latpre + (size_t)2048 * 512;

  const dim3 B(256);
  const float qscale = 0.08838834764831845f;     // 1/sqrt(128)

  cvt_f2b<<<dim3(8192), B, 0, stream>>>(x, xb);
  cvt_transpose<<<dim3(32, 32), B, 0, stream>>>(Wq,    WqT, 2048, 2048);
  cvt_transpose<<<dim3(8,  32), B, 0, stream>>>(Wdown, WdT, 2048, 512);
  // q = (x@Wq) * qscale ; latpre = x@Wdown
  gemm128<bf16_t><<<dim3(16, 32), B, 0, stream>>>(xb, WqT, qbuf, 4096, 2048, 2048, qscale, 0, 0);
  gemm128<bf16_t><<<dim3(4,  32), B, 0, stream>>>(xb, WdT, latpre, 4096, 512, 2048, 1.0f, 0, 0);
  // latent cache
  copy_prev_f<<<dim3(2048), B, 0, stream>>>(lat_prev, latent);
  ln_kernel<<<dim3(4096), B, 0, stream>>>(latpre, ln_g, ln_b, latent);
  // weight transposes into dead regions (stream order enforces lifetimes)
  cvt_transpose<<<dim3(32, 32), B, 0, stream>>>(Wo,    WoT, 2048, 2048);
  cvt_transpose<<<dim3(32, 8),  B, 0, stream>>>(Wk_up, WkT, 512, 2048);
  cvt_transpose<<<dim3(32, 8),  B, 0, stream>>>(Wv_up, WvT, 512, 2048);
  // k = latent @ Wk_up  (rows b*4096+s)
  gemm128<bf16_t><<<dim3(16, 64), B, 0, stream>>>(latent, WkT, kbuf, 8192, 2048, 512, 1.0f, 0, 0);
  // vT_b = WvT @ latent_b^T  (BT = latent_b), batched over z
  gemm128<bf16_t><<<dim3(32, 16, 2), B, 0, stream>>>(WvT, latent, vTb, 2048, 4096, 512, 1.0f,
                                                     (long long)4096 * 512,
                                                     (long long)2048 * 4096);
  // attention
  attn2<<<dim3(16, 16, 2), B, 0, stream>>>(qbuf, kbuf, vTb, aout);
  // output projection (fp32 out)
  gemm128<float><<<dim3(16, 32), B, 0, stream>>>(aout, WoT, out, 4096, 2048, 2048, 1.0f, 0, 0);
}

// Round 5
// 588.520 us; speedup vs baseline: 1.6905x; 1.0837x over previous
//
#include <hip/hip_runtime.h>
#include <hip/hip_bf16.h>

using bf16_t = __bf16;
typedef __bf16 bf16x8 __attribute__((ext_vector_type(8)));
typedef __bf16 bf16x4 __attribute__((ext_vector_type(4)));
typedef __bf16 bf16x2 __attribute__((ext_vector_type(2)));
typedef float  f32x4  __attribute__((ext_vector_type(4)));
typedef float  f32x16 __attribute__((ext_vector_type(16)));
typedef unsigned u32x4 __attribute__((ext_vector_type(4)));

#define MFMA16(a,b,c) __builtin_amdgcn_mfma_f32_16x16x32_bf16((a),(b),(c),0,0,0)
#define MFMA32(a,b,c) __builtin_amdgcn_mfma_f32_32x32x16_bf16((a),(b),(c),0,0,0)

__device__ __forceinline__ void load_lds16(const void* g, void* l) {
  __builtin_amdgcn_global_load_lds(
      (const __attribute__((address_space(1))) unsigned int*)g,
      (__attribute__((address_space(3))) unsigned int*)l, 16, 0, 0);
}

__device__ __forceinline__ unsigned pack_bf16(float a, float b) {
  union { bf16x2 v; unsigned u; } c;
  c.v[0] = (bf16_t)a; c.v[1] = (bf16_t)b;
  return c.u;
}

// ---------------------------------------------------------------------------
// fp32 -> bf16 elementwise convert (x). 4 elems/thread.
// ---------------------------------------------------------------------------
__global__ __launch_bounds__(256) void cvt_f2b(const float* __restrict__ in,
                                               bf16_t* __restrict__ out)
{
  const size_t i = ((size_t)blockIdx.x * 256 + threadIdx.x) * 4;
  f32x4 d = *(const f32x4*)(in + i);
  bf16x4 o;
#pragma unroll
  for (int j = 0; j < 4; ++j) o[j] = (bf16_t)d[j];
  *(bf16x4*)(out + i) = o;
}

// ---------------------------------------------------------------------------
// fp32 [R][C] -> bf16 [C][R] transposed convert (weights). 64x64 LDS tile.
// ---------------------------------------------------------------------------
__global__ __launch_bounds__(256) void cvt_transpose(const float* __restrict__ in,
                                                     bf16_t* __restrict__ out,
                                                     int R, int C)
{
  __shared__ __align__(16) bf16_t t[64 * 80];
  const int r0 = blockIdx.y * 64, c0 = blockIdx.x * 64;
  const int rr = threadIdx.x >> 4;          // 0..15
  const int c4 = (threadIdx.x & 15) * 4;    // 0..60
#pragma unroll
  for (int i = 0; i < 4; ++i) {
    const int r = rr + i * 16;
    f32x4 d = *(const f32x4*)(in + (size_t)(r0 + r) * C + c0 + c4);
#pragma unroll
    for (int j = 0; j < 4; ++j) t[(c4 + j) * 80 + r] = (bf16_t)d[j];
  }
  __syncthreads();
  const int a  = threadIdx.x >> 3;          // 0..31
  const int bc = (threadIdx.x & 7) * 8;
#pragma unroll
  for (int half = 0; half < 2; ++half) {
    const int cc = a + half * 32;
    bf16x8 d = *(const bf16x8*)&t[cc * 80 + bc];
    *(bf16x8*)(out + (size_t)(c0 + cc) * R + r0 + bc) = d;
  }
}

// ---------------------------------------------------------------------------
// m97-class GEMM: C[M,N] = A[M,K] @ B[K,N] (+scale), B given as BT[N,K].
// 128x128 tile, BK=32, 4 waves each 64x64 (4x4 of 16x16x32 MFMA).
// Staging via global_load_lds dwordx4 with XOR chunk swizzle.
// ---------------------------------------------------------------------------
template <typename OutT>
__global__ __launch_bounds__(256) void gemm128(const bf16_t* __restrict__ A,
                                               const bf16_t* __restrict__ BT,
                                               OutT* __restrict__ C,
                                               int M, int N, int K, float scale,
                                               long long zB, long long zC)
{
  __shared__ __align__(16) bf16_t As[128 * 32];
  __shared__ __align__(16) bf16_t Bs[128 * 32];
  const int tid = threadIdx.x;
  BT += (size_t)blockIdx.z * zB;
  C  += (size_t)blockIdx.z * zC;
  const int m0 = blockIdx.y * 128, n0 = blockIdx.x * 128;
  const int lane = tid & 63, w = tid >> 6;
  const int quad = lane >> 4, l15 = lane & 15;
  const int wm = (w >> 1) * 64, wn = (w & 1) * 64;
  const int s_row = tid >> 2;
  const int g_off = ((tid & 3) ^ (s_row & 3)) * 8;   // swizzled global chunk
  const int quadp = (quad ^ (l15 & 3)) * 8;          // swizzled frag offset
  const bf16_t* Ap0 = A  + (size_t)(m0 + s_row) * K + g_off;
  const bf16_t* Ap1 = A  + (size_t)(m0 + 64 + s_row) * K + g_off;
  const bf16_t* Bp0 = BT + (size_t)(n0 + s_row) * K + g_off;
  const bf16_t* Bp1 = BT + (size_t)(n0 + 64 + s_row) * K + g_off;

  f32x4 acc[4][4] = {};

  for (int k0 = 0; k0 < K; k0 += 32) {
    __syncthreads();
    load_lds16(Ap0 + k0, As + tid * 8);
    load_lds16(Ap1 + k0, As + tid * 8 + 2048);
    load_lds16(Bp0 + k0, Bs + tid * 8);
    load_lds16(Bp1 + k0, Bs + tid * 8 + 2048);
    __syncthreads();
    bf16x8 af[4], bfr[4];
#pragma unroll
    for (int fi = 0; fi < 4; ++fi)
      af[fi] = *(const bf16x8*)&As[(wm + fi * 16 + l15) * 32 + quadp];
#pragma unroll
    for (int fj = 0; fj < 4; ++fj)
      bfr[fj] = *(const bf16x8*)&Bs[(wn + fj * 16 + l15) * 32 + quadp];
#pragma unroll
    for (int fi = 0; fi < 4; ++fi)
#pragma unroll
      for (int fj = 0; fj < 4; ++fj)
        acc[fi][fj] = MFMA16(af[fi], bfr[fj], acc[fi][fj]);
  }

#pragma unroll
  for (int fi = 0; fi < 4; ++fi)
#pragma unroll
    for (int fj = 0; fj < 4; ++fj)
#pragma unroll
      for (int r = 0; r < 4; ++r) {
        const int row = m0 + wm + fi * 16 + quad * 4 + r;
        const int col = n0 + wn + fj * 16 + l15;
        C[(size_t)row * N + col] = (OutT)(acc[fi][fj][r] * scale);
      }
}

// ---------------------------------------------------------------------------
// latent_prev fp32 (2,2048,512) -> bf16 latent rows [0,2048) of (2,4096,512)
// ---------------------------------------------------------------------------
__global__ __launch_bounds__(256) void copy_prev_f(const float* __restrict__ prev,
                                                   bf16_t* __restrict__ latent)
{
  const size_t v    = (size_t)blockIdx.x * 256 + threadIdx.x;
  const size_t flat = v * 4;
  const size_t per  = (size_t)2048 * 512;
  const size_t b    = flat / per, rem = flat % per;
  f32x4 d = *(const f32x4*)(prev + flat);
  bf16x4 o;
#pragma unroll
  for (int j = 0; j < 4; ++j) o[j] = (bf16_t)d[j];
  *(bf16x4*)(latent + b * ((size_t)4096 * 512) + rem) = o;
}

// ---------------------------------------------------------------------------
// LayerNorm over 512 (fp32 stats), bf16 in, fp32 g/b, bf16 out into latent
// rows [2048,4096).
// ---------------------------------------------------------------------------
__global__ __launch_bounds__(256) void ln_kernel(const bf16_t* __restrict__ in,
                                                 const float* __restrict__ g_,
                                                 const float* __restrict__ b_,
                                                 bf16_t* __restrict__ latent)
{
  const int row = blockIdx.x;             // 0..4095 (= b*2048 + t)
  const int tid = threadIdx.x;
  const float x0 = (float)in[(size_t)row * 512 + tid];
  const float x1 = (float)in[(size_t)row * 512 + 256 + tid];
  float s  = x0 + x1;
  float sq = x0 * x0 + x1 * x1;
#pragma unroll
  for (int off = 1; off < 64; off <<= 1) {
    s  += __shfl_xor(s, off);
    sq += __shfl_xor(sq, off);
  }
  __shared__ float red[8];
  const int w = tid >> 6;
  if ((tid & 63) == 0) { red[w] = s; red[4 + w] = sq; }
  __syncthreads();
  s  = red[0] + red[1] + red[2] + red[3];
  sq = red[4] + red[5] + red[6] + red[7];
  const float mu   = s * (1.0f / 512.0f);
  const float var  = sq * (1.0f / 512.0f) - mu * mu;
  const float rstd = rsqrtf(var + 1e-5f);
  const int b = row >> 11, tt = row & 2047;
  bf16_t* outp = latent + ((size_t)b * 4096 + 2048 + tt) * 512;
  outp[tid]       = (bf16_t)((x0 - mu) * rstd * g_[tid]       + b_[tid]);
  outp[tid + 256] = (bf16_t)((x1 - mu) * rstd * g_[tid + 256] + b_[tid + 256]);
}

// ---------------------------------------------------------------------------
// Flash attention v3. grid (t/128, H, b); 4 waves; per-lane query column.
// S^T = K·Q^T via 32x32x16 MFMA -> in-register softmax; PV via in-register
// P^T build (shfl_xor 32, no LDS round-trip). K/V double-buffered via
// global_load_lds (stage next tile during current compute; 1 barrier/iter).
// qt anti-correlated across b for per-CU load balance.
// LDS element offsets (bf16): Ks = cur*8192, Vs = 16384 + cur*8192.
// ---------------------------------------------------------------------------
__global__ __launch_bounds__(256) void attn3(const bf16_t* __restrict__ q,
                                             const bf16_t* __restrict__ k,
                                             const bf16_t* __restrict__ vT,
                                             bf16_t* __restrict__ out)
{
  __shared__ __align__(16) bf16_t smem[32768];      // Ks0|Ks1|Vs0|Vs1 overlay

  const int tid = threadIdx.x;
  const int lane = tid & 63, w = tid >> 6;
  const int l31 = lane & 31, h5 = lane >> 5;
  int qt = blockIdx.x;
  if (blockIdx.z) qt = 15 - qt;                     // balance: pair 34+64 tiles
  const int h = blockIdx.y, b = blockIdx.z;
  const int q0 = qt * 128;
  const int qg = q0 + l31 * 4 + w;                  // this lane's query row

  // Q^T B-frags: B[k=feat fc*16+h5*8+j][n=q l31]
  bf16x8 qf[8];
  const bf16_t* qb = q + ((size_t)(b * 2048 + qg)) * 2048 + h * 128 + h5 * 8;
#pragma unroll
  for (int fc = 0; fc < 8; ++fc) qf[fc] = *(const bf16x8*)(qb + fc * 16);

  const bf16_t* kbase = k + ((size_t)b * 4096) * 2048 + h * 128;
  const bf16_t* vbase = vT + ((size_t)(b * 16 + h)) * 128 * 4096;

  // staging maps (slot = tid + 256p)
  int ks_key[4], ks_go[4], vs_feat[4], vs_go[4];
#pragma unroll
  for (int p = 0; p < 4; ++p) {
    const int slot = tid + 256 * p;
    const int key = slot >> 4, ph = slot & 15;
    ks_key[p] = key;
    ks_go[p]  = (((ph & 8) | ((ph & 7) ^ (key & 7)))) * 8;
    const int ft = slot >> 3, p2 = slot & 7;
    vs_feat[p] = ft;
    vs_go[p]   = (p2 ^ (ft & 7)) * 8;
  }
  // frag read offsets (elems)
  int kfo[8], vfo[4];
#pragma unroll
  for (int fc = 0; fc < 8; ++fc) {
    const int L = fc * 2 + h5;
    kfo[fc] = l31 * 128 + ((L & 8) | ((L & 7) ^ (l31 & 7))) * 8;
  }
#pragma unroll
  for (int kc = 0; kc < 4; ++kc) {
    const int L = kc * 2 + h5;
    vfo[kc] = l31 * 64 + (L ^ (l31 & 7)) * 8;
  }

  f32x16 o[4] = {};
  float m = -1e30f, l = 0.f;
  const int send = 2048 + q0 + 128;

  // prologue: stage tile 0 into buffer 0
#pragma unroll
  for (int p = 0; p < 4; ++p) {
    load_lds16(kbase + (size_t)ks_key[p] * 2048 + ks_go[p],
               smem + (tid + 256 * p) * 8);
    load_lds16(vbase + (size_t)vs_feat[p] * 4096 + vs_go[p],
               smem + 16384 + (tid + 256 * p) * 8);
  }
  __syncthreads();                                  // tile 0 resident

  int cur = 0;
  for (int s0 = 0; s0 < send; s0 += 64) {
    // stage next tile into the other buffer (DMA overlaps compute below)
    const int s1 = s0 + 64;
    if (s1 < send) {
      const int nxt = (cur ^ 1) * 8192;
#pragma unroll
      for (int p = 0; p < 4; ++p) {
        load_lds16(kbase + (size_t)(s1 + ks_key[p]) * 2048 + ks_go[p],
                   smem + nxt + (tid + 256 * p) * 8);
        load_lds16(vbase + (size_t)vs_feat[p] * 4096 + s1 + vs_go[p],
                   smem + 16384 + nxt + (tid + 256 * p) * 8);
      }
    }
    const bf16_t* Kc = smem + cur * 8192;
    const bf16_t* Vc = smem + 16384 + cur * 8192;

    // S^T tiles: rows = keys 32t + (i&3)+8*(i>>2)+4*h5, col = q = l31
    f32x16 st[2] = {};
#pragma unroll
    for (int fc = 0; fc < 8; ++fc) {
      bf16x8 k0 = *(const bf16x8*)&Kc[kfo[fc]];
      bf16x8 k1 = *(const bf16x8*)&Kc[4096 + kfo[fc]];
      st[0] = MFMA32(k0, qf[fc], st[0]);
      st[1] = MFMA32(k1, qf[fc], st[1]);
    }

    if (s0 + 63 > 2048 + q0) {                      // causal tail masking
#pragma unroll
      for (int t = 0; t < 2; ++t)
#pragma unroll
        for (int i = 0; i < 16; ++i) {
          const int key = s0 + 32 * t + (i & 3) + 8 * (i >> 2) + 4 * h5;
          if (key > 2048 + qg) st[t][i] = -1e30f;
        }
    }

    // in-register max over this lane's 32 scores + partner half
    float mt = st[0][0];
#pragma unroll
    for (int i = 1; i < 16; ++i) mt = fmaxf(mt, st[0][i]);
#pragma unroll
    for (int i = 0; i < 16; ++i) mt = fmaxf(mt, st[1][i]);
    mt = fmaxf(mt, __shfl_xor(mt, 32));

    if (__any(mt > m)) {
      const float mnew = fmaxf(m, mt);
      const float alpha = __expf(m - mnew);
#pragma unroll
      for (int ft = 0; ft < 4; ++ft)
#pragma unroll
        for (int i = 0; i < 16; ++i) o[ft][i] *= alpha;
      l *= alpha;
      m = mnew;
    }

    // exp + pack P into u32 pairs; group g holds keys 32t + 8g + 4h5 + 0..3
    float rs = 0.f;
    unsigned up[2][4][2];
#pragma unroll
    for (int t = 0; t < 2; ++t)
#pragma unroll
      for (int g = 0; g < 4; ++g) {
        const float p0 = __expf(st[t][4 * g + 0] - m);
        const float p1 = __expf(st[t][4 * g + 1] - m);
        const float p2 = __expf(st[t][4 * g + 2] - m);
        const float p3 = __expf(st[t][4 * g + 3] - m);
        rs += (p0 + p1) + (p2 + p3);
        up[t][g][0] = pack_bf16(p0, p1);
        up[t][g][1] = pack_bf16(p2, p3);
      }
    rs += __shfl_xor(rs, 32);
    l += rs;

    // out^T += V^T · P^T ; P^T B-frag built in-register via half-exchange
#pragma unroll
    for (int kc = 0; kc < 4; ++kc) {
      const int t = kc >> 1, gp = (kc & 1) * 2;
      const unsigned a0 = up[t][gp][0],     a1 = up[t][gp][1];
      const unsigned b0 = up[t][gp + 1][0], b1 = up[t][gp + 1][1];
      const unsigned xa0 = __shfl_xor(a0, 32), xa1 = __shfl_xor(a1, 32);
      const unsigned xb0 = __shfl_xor(b0, 32), xb1 = __shfl_xor(b1, 32);
      u32x4 uw;
      uw[0] = h5 ? xb0 : a0;
      uw[1] = h5 ? xb1 : a1;
      uw[2] = h5 ? b0 : xa0;
      uw[3] = h5 ? b1 : xa1;
      union { u32x4 u; bf16x8 v; } pc; pc.u = uw;
      const bf16x8 pf = pc.v;
#pragma unroll
      for (int ft = 0; ft < 4; ++ft) {
        bf16x8 vf = *(const bf16x8*)&Vc[ft * 2048 + vfo[kc]];
        o[ft] = MFMA32(vf, pf, o[ft]);
      }
    }

    __syncthreads();   // compute reads done + next-tile DMA drained
    cur ^= 1;
  }

  // epilogue: normalize, LDS transpose, coalesced store (smem overlay)
  const float inv = 1.0f / l;
  const int rowp_w = w * 32 + l31;
#pragma unroll
  for (int ft = 0; ft < 4; ++ft)
#pragma unroll
    for (int g = 0; g < 4; ++g) {
      bf16x4 pk;
#pragma unroll
      for (int r = 0; r < 4; ++r) pk[r] = (bf16_t)(o[ft][4 * g + r] * inv);
      *(bf16x4*)&smem[rowp_w * 136 + ft * 32 + g * 8 + h5 * 4] = pk;
    }
  __syncthreads();
#pragma unroll
  for (int p = 0; p < 8; ++p) {
    const int c = tid + 256 * p;
    const int rowp = c >> 4, chk = c & 15;
    const int ql = (rowp & 31) * 4 + (rowp >> 5);
    bf16x8 d = *(const bf16x8*)&smem[rowp * 136 + chk * 8];
    *(bf16x8*)(out + ((size_t)(b * 2048 + q0 + ql)) * 2048 + h * 128 + chk * 8) = d;
  }
}

// ---------------------------------------------------------------------------
extern "C" void kernel_launch(void* const* d_in, const int* in_sizes, int n_in,
                              void* d_out, int out_size, void* d_ws, size_t ws_size,
                              hipStream_t stream)
{
  (void)in_sizes; (void)n_in; (void)out_size; (void)ws_size;
  const float* x        = (const float*)d_in[0];
  const float* lat_prev = (const float*)d_in[1];
  const float* Wq       = (const float*)d_in[2];
  const float* Wdown    = (const float*)d_in[3];
  const float* Wk_up    = (const float*)d_in[4];
  const float* Wv_up    = (const float*)d_in[5];
  const float* ln_g     = (const float*)d_in[6];
  const float* ln_b     = (const float*)d_in[7];
  const float* Wo       = (const float*)d_in[8];
  float* out = (float*)d_out;

  char* p = (char*)d_ws;
  auto alloc = [&](size_t elems) { bf16_t* r = (bf16_t*)p; p += elems * 2; return r; };
  bf16_t* xb     = alloc((size_t)4096 * 2048);   // hosts WoT after x dead
  bf16_t* WqT    = alloc((size_t)2048 * 2048);
  bf16_t* WdT    = alloc((size_t)512 * 2048);
  bf16_t* qbuf   = alloc((size_t)4096 * 2048);
  bf16_t* latpre = alloc((size_t)4096 * 512);    // hosts WkT+WvT after LN
  bf16_t* latent = alloc((size_t)2 * 4096 * 512);
  bf16_t* kbuf   = alloc((size_t)8192 * 2048);
  bf16_t* vTb    = alloc((size_t)2 * 2048 * 4096);
  bf16_t* aout   = alloc((size_t)4096 * 2048);
  bf16_t* WoT  = xb;
  bf16_t* WkT  = latpre;
  bf16_t* WvT  = latpre + (size_t)2048 * 512;

  const dim3 B(256);
  const float qscale = 0.08838834764831845f;     // 1/sqrt(128)

  cvt_f2b<<<dim3(8192), B, 0, stream>>>(x, xb);
  cvt_transpose<<<dim3(32, 32), B, 0, stream>>>(Wq,    WqT, 2048, 2048);
  cvt_transpose<<<dim3(8,  32), B, 0, stream>>>(Wdown, WdT, 2048, 512);
  // q = (x@Wq) * qscale ; latpre = x@Wdown
  gemm128<bf16_t><<<dim3(16, 32), B, 0, stream>>>(xb, WqT, qbuf, 4096, 2048, 2048, qscale, 0, 0);
  gemm128<bf16_t><<<dim3(4,  32), B, 0, stream>>>(xb, WdT, latpre, 4096, 512, 2048, 1.0f, 0, 0);
  // latent cache
  copy_prev_f<<<dim3(2048), B, 0, stream>>>(lat_prev, latent);
  ln_kernel<<<dim3(4096), B, 0, stream>>>(latpre, ln_g, ln_b, latent);
  // weight transposes into dead regions (stream order enforces lifetimes)
  cvt_transpose<<<dim3(32, 32), B, 0, stream>>>(Wo,    WoT, 2048, 2048);
  cvt_transpose<<<dim3(32, 8),  B, 0, stream>>>(Wk_up, WkT, 512, 2048);
  cvt_transpose<<<dim3(32, 8),  B, 0, stream>>>(Wv_up, WvT, 512, 2048);
  // k = latent @ Wk_up  (rows b*4096+s)
  gemm128<bf16_t><<<dim3(16, 64), B, 0, stream>>>(latent, WkT, kbuf, 8192, 2048, 512, 1.0f, 0, 0);
  // vT_b = WvT @ latent_b^T  (BT = latent_b), batched over z
  gemm128<bf16_t><<<dim3(32, 16, 2), B, 0, stream>>>(WvT, latent, vTb, 2048, 4096, 512, 1.0f,
                                                     (long long)4096 * 512,
                                                     (long long)2048 * 4096);
  // attention
  attn3<<<dim3(16, 16, 2), B, 0, stream>>>(qbuf, kbuf, vTb, aout);
  // output projection (fp32 out)
  gemm128<float><<<dim3(16, 32), B, 0, stream>>>(aout, WoT, out, 4096, 2048, 2048, 1.0f, 0, 0);
}